// Round 9
// baseline (2452.741 us; speedup 1.0000x reference)
//
#include <hip/hip_runtime.h>

#define SS 1024
#define BB 2048
#define NT 256
#define GRID 1024  // 2 batches/block, 2 waves/batch (fwd-cells wave + bwd-cells wave)

typedef unsigned int u32;
typedef unsigned short u16;
typedef _Float16 half2v __attribute__((ext_vector_type(2)));
typedef __fp16 fp16x2 __attribute__((ext_vector_type(2)));

#define LDS_FENCE() asm volatile("s_waitcnt lgkmcnt(0)" ::: "memory")

// ---------- helpers ----------
__device__ __forceinline__ u16 f2bf(float f) {  // RNE fp32->bf16
  u32 u = __float_as_uint(f);
  return (u16)((u + 0x7fffu + ((u >> 16) & 1u)) >> 16);
}
template<bool BFM>
__device__ __forceinline__ float ldin(const void* p, int i) {
  if (BFM) { u16 v = ((const u16*)p)[i]; return __uint_as_float(((u32)v) << 16); }
  return ((const float*)p)[i];
}
__device__ __forceinline__ u32 packrtz(float lo, float hi) {
#if __has_builtin(__builtin_amdgcn_cvt_pkrtz)
  fp16x2 h = __builtin_amdgcn_cvt_pkrtz(lo, hi);
  return __builtin_bit_cast(u32, h);
#else
  _Float16 ha = (_Float16)lo, hb = (_Float16)hi;
  return (u32)__builtin_bit_cast(u16, ha) | ((u32)__builtin_bit_cast(u16, hb) << 16);
#endif
}
template<bool BFM>
__device__ __forceinline__ u32 ldpack(const void* p, int i) {  // elems {i,i+1} -> f16x2
  if (BFM) {
    u32 pr = *(const u32*)((const u16*)p + i);
    return packrtz(__uint_as_float(pr << 16), __uint_as_float(pr & 0xffff0000u));
  }
  return packrtz(((const float*)p)[i], ((const float*)p)[i + 1]);
}
__device__ __forceinline__ float sigf(float x) {
  return __builtin_amdgcn_rcpf(1.0f + __expf(-x));
}
__device__ __forceinline__ float tanh_f(float x) {
  return 1.0f - 2.0f * __builtin_amdgcn_rcpf(__expf(2.0f * x) + 1.0f);
}
__device__ __forceinline__ float combine4(float a0, float a1, float a2, float a3, float& c) {
  float ig = sigf(a0);
  float fg = sigf(a1);
  float gg = tanh_f(a2);
  float og = sigf(a3);
  c = fg * c + ig * gg;
  return og * tanh_f(c);
}
__device__ __forceinline__ float dot2f(u32 w, u32 h, float acc) {
#if __has_builtin(__builtin_amdgcn_fdot2)
  return __builtin_amdgcn_fdot2(__builtin_bit_cast(half2v, w),
                                __builtin_bit_cast(half2v, h), acc, false);
#else
  half2v a = __builtin_bit_cast(half2v, w), b = __builtin_bit_cast(half2v, h);
  acc = fmaf((float)a.x, (float)b.x, acc);
  return fmaf((float)a.y, (float)b.y, acc);
#endif
}

// ---- 96 scalar u32 weight regs/lane (no arrays/vectors -> 1-reg SSA intervals) ----
#define DECL8(P) u32 P##0, P##1, P##2, P##3, P##4, P##5, P##6, P##7;
#define STG8(P, SRC, R)              \
  P##0 = ldpack<BFM>(SRC, (R) + 0);  \
  P##1 = ldpack<BFM>(SRC, (R) + 2);  \
  P##2 = ldpack<BFM>(SRC, (R) + 4);  \
  P##3 = ldpack<BFM>(SRC, (R) + 6);  \
  P##4 = ldpack<BFM>(SRC, (R) + 8);  \
  P##5 = ldpack<BFM>(SRC, (R) + 10); \
  P##6 = ldpack<BFM>(SRC, (R) + 12); \
  P##7 = ldpack<BFM>(SRC, (R) + 14);
#define DOT8(A, P, HA, HB)      \
  A = dot2f(P##0, HA.x, A);     \
  A = dot2f(P##1, HA.y, A);     \
  A = dot2f(P##2, HA.z, A);     \
  A = dot2f(P##3, HA.w, A);     \
  A = dot2f(P##4, HB.x, A);     \
  A = dot2f(P##5, HB.y, A);     \
  A = dot2f(P##6, HB.z, A);     \
  A = dot2f(P##7, HB.w, A);

template<bool BFM>
__device__ __forceinline__ void run(
    const void* xg,
    const void* Wih_f0, const void* Whh_f0, const void* b_f0,
    const void* Wih_f1, const void* Whh_f1, const void* b_f1,
    const void* Wih_b0, const void* Whh_b0, const void* b_b0,
    const void* Wih_b1, const void* Whh_b1, const void* b_b1,
    const void* Wlin, const void* blin, const int* futp, void* outp,
    _Float16 (*h0s)[32], _Float16 (*h1s)[2][32], float (*h1p)[2],
    int tid, int bid) {
  const int wv = tid >> 6, lane = tid & 63;
  const int j = lane & 31, half = lane >> 5;  // half: which K-half this lane owns
  const int dirw = wv & 1;                    // wave-uniform: 0 = f0/f1 cells, 1 = b0/b1
  const int bb = wv >> 1;                     // batch-in-block
  const int gb = bid * 2 + bb;                // global batch

  const void* s0  = dirw ? Whh_b0 : Whh_f0;   // all wave-uniform selects
  const void* sA  = dirw ? Wih_b1 : Wih_f1;
  const void* sB  = dirw ? Whh_b1 : Whh_f1;
  const void* pb0 = dirw ? b_b0 : b_f0;
  const void* pb1 = dirw ? b_b1 : b_f1;
  const void* pwx = dirw ? Wih_b0 : Wih_f0;

  // ---- stage 96 dw of weights: gate g, row (g*32+j), K-elems [half*32, half*32+32) ----
  DECL8(w0g0) DECL8(w0g1) DECL8(w0g2) DECL8(w0g3)   // layer-0 rec
  DECL8(wAg0) DECL8(wAg1) DECL8(wAg2) DECL8(wAg3)   // layer-1 inp
  DECL8(wBg0) DECL8(wBg1) DECL8(wBg2) DECL8(wBg3)   // layer-1 rec
  {
    const int rb = j * 32 + half * 16;  // half*16 elems = 8 dw
    STG8(w0g0, s0, rb + 0)    STG8(w0g1, s0, rb + 1024)
    STG8(w0g2, s0, rb + 2048) STG8(w0g3, s0, rb + 3072)
    STG8(wAg0, sA, rb + 0)    STG8(wAg1, sA, rb + 1024)
    STG8(wAg2, sA, rb + 2048) STG8(wAg3, sA, rb + 3072)
    STG8(wBg0, sB, rb + 0)    STG8(wBg1, sB, rb + 1024)
    STG8(wBg2, sB, rb + 2048) STG8(wBg3, sB, rb + 3072)
  }
  // layer-0 (wx|b0) packed: added once, AFTER the cross-half reduction
  const u32 wb0_0 = packrtz(ldin<BFM>(pwx, 0 * 32 + j), ldin<BFM>(pb0, 0 * 32 + j));
  const u32 wb0_1 = packrtz(ldin<BFM>(pwx, 1 * 32 + j), ldin<BFM>(pb0, 1 * 32 + j));
  const u32 wb0_2 = packrtz(ldin<BFM>(pwx, 2 * 32 + j), ldin<BFM>(pb0, 2 * 32 + j));
  const u32 wb0_3 = packrtz(ldin<BFM>(pwx, 3 * 32 + j), ldin<BFM>(pb0, 3 * 32 + j));
  const float b1_0 = ldin<BFM>(pb1, 0 * 32 + j);
  const float b1_1 = ldin<BFM>(pb1, 1 * 32 + j);
  const float b1_2 = ldin<BFM>(pb1, 2 * 32 + j);
  const float b1_3 = ldin<BFM>(pb1, 3 * 32 + j);
  const float wl  = ldin<BFM>(Wlin, dirw * 32 + j);
  const float blv = ldin<BFM>(blin, 0);
  const int fut = *futp;

  _Float16* const my0 = &h0s[wv][0];  // own layer-0 h row (private to this wave)

  // zero h state
  if (!half) {
    my0[j] = (_Float16)0.f;
    if (!dirw) { h1s[0][bb][j] = (_Float16)0.f; h1s[1][bb][j] = (_Float16)0.f; }
  }

  // fwd wave computes step t=u; bwd wave runs one step skewed (t'=u-1).
  // hf1 rows parity-double-buffered; one __syncthreads per iteration bounds drift.
  float c0 = 0.f, c1 = 0.f;
  float x_cur = ldin<BFM>(xg, (dirw ? ((fut + 1) & (SS - 1)) : 0) * BB + gb);

  for (int u = 0; u <= SS; ++u) {
    __syncthreads();  // publishes iter u-1's hf1/partial; licenses slot u&1 overwrite

    int idxn = dirw ? ((fut - u) & (SS - 1)) : ((u + 1 < SS) ? (u + 1) : (SS - 1));
    float x_n = ldin<BFM>(xg, idxn * BB + gb);

    // ---- layer 0 (fwd: f0@u ; bwd: b0@u-1) — own K-half, then reduce ----
    float a0 = 0.f, a1 = 0.f, a2 = 0.f, a3 = 0.f;
    {
      const uint4* hp = (const uint4*)my0;
      uint4 hq0 = hp[half * 2], hq1 = hp[half * 2 + 1];
      DOT8(a0, w0g0, hq0, hq1)
      DOT8(a1, w0g1, hq0, hq1)
      DOT8(a2, w0g2, hq0, hq1)
      DOT8(a3, w0g3, hq0, hq1)
    }
    a0 += __shfl_xor(a0, 32); a1 += __shfl_xor(a1, 32);
    a2 += __shfl_xor(a2, 32); a3 += __shfl_xor(a3, 32);
    {
      const u32 xpk = packrtz(x_cur, 1.0f);
      a0 = dot2f(wb0_0, xpk, a0);
      a1 = dot2f(wb0_1, xpk, a1);
      a2 = dot2f(wb0_2, xpk, a2);
      a3 = dot2f(wb0_3, xpk, a3);
    }
    float hn0 = combine4(a0, a1, a2, a3, c0);
    if ((u == 0) && dirw) { hn0 = 0.f; c0 = 0.f; }  // bwd u=0 computed t'=-1 garbage
    if (!half) my0[j] = (_Float16)hn0;
    LDS_FENCE();

    // ---- layer 1 (fwd: f1@u rec=hf1(u-1) ; bwd: b1@u-1 rec=NEW hf1(u-1) per ref bug) ----
    a0 = 0.f; a1 = 0.f; a2 = 0.f; a3 = 0.f;
    {
      const uint4* hp = (const uint4*)my0;                    // inp: own new layer-0 h
      uint4 nq0 = hp[half * 2], nq1 = hp[half * 2 + 1];
      const uint4* rp = (const uint4*)&h1s[(u + 1) & 1][bb][0];  // slot (u-1)&1
      uint4 rq0 = rp[half * 2], rq1 = rp[half * 2 + 1];
      DOT8(a0, wAg0, nq0, nq1)
      DOT8(a1, wAg1, nq0, nq1)
      DOT8(a2, wAg2, nq0, nq1)
      DOT8(a3, wAg3, nq0, nq1)
      DOT8(a0, wBg0, rq0, rq1)
      DOT8(a1, wBg1, rq0, rq1)
      DOT8(a2, wBg2, rq0, rq1)
      DOT8(a3, wBg3, rq0, rq1)
    }
    a0 += __shfl_xor(a0, 32); a1 += __shfl_xor(a1, 32);
    a2 += __shfl_xor(a2, 32); a3 += __shfl_xor(a3, 32);
    a0 += b1_0; a1 += b1_1; a2 += b1_2; a3 += b1_3;
    float hn1 = combine4(a0, a1, a2, a3, c1);
    if ((u == 0) && dirw) c1 = 0.f;

    // ---- publish hf1 / head partial (fwd) or write output (bwd) ----
    float contrib = half ? 0.f : (wl * hn1);
#pragma unroll
    for (int m = 1; m <= 32; m <<= 1) contrib += __shfl_xor(contrib, m, 64);
    if (!dirw) {
      if (!half) h1s[u & 1][bb][j] = (_Float16)hn1;   // hf1(u) -> slot u&1
      if (lane == 0) h1p[u & 1][bb] = contrib;        // sum_j wlin[j]*hf1(u)[j]
    } else {
      if (lane == 0 && u > 0) {
        float o = contrib + h1p[(u + 1) & 1][bb] + blv;  // + fwd partial of hf1(u-1)
        size_t pos = (size_t)gb * SS + (size_t)(u - 1);
        if (BFM) ((u16*)outp)[pos] = f2bf(o);
        else     ((float*)outp)[pos] = o;
      }
    }
    x_cur = x_n;
  }
}

__global__ __launch_bounds__(NT) void lstm_kernel(
    const void* __restrict__ xg,
    const void* Wih_f0, const void* Whh_f0, const void* b_f0,
    const void* Wih_f1, const void* Whh_f1, const void* b_f1,
    const void* Wih_b0, const void* Whh_b0, const void* b_b0,
    const void* Wih_b1, const void* Whh_b1, const void* b_b1,
    const void* Wlin, const void* blin, const int* __restrict__ futp,
    void* __restrict__ outp) {
  __shared__ __align__(16) _Float16 h0s[4][32];     // per-wave layer-0 h row
  __shared__ __align__(16) _Float16 h1s[2][2][32];  // [parity][batch-in-block] hf1 row
  __shared__ float h1p[2][2];                       // [parity][bb] head partial

  // dtype detection (uniform): bf16-pairs read as fp32 are implausible as N(0,1)
  bool bfm;
  {
    const float* xf = (const float*)xg;
    int bad = 0;
    for (int i = 0; i < 64; ++i) {
      float a = fabsf(xf[i]);
      bool ok = (a == 0.0f) || (a > 1e-8f && a < 1e4f);
      if (!ok) bad = 1;
    }
    bfm = (bad != 0);
  }

  if (bfm)
    run<true>(xg, Wih_f0, Whh_f0, b_f0, Wih_f1, Whh_f1, b_f1,
              Wih_b0, Whh_b0, b_b0, Wih_b1, Whh_b1, b_b1,
              Wlin, blin, futp, outp, h0s, h1s, h1p, threadIdx.x, blockIdx.x);
  else
    run<false>(xg, Wih_f0, Whh_f0, b_f0, Wih_f1, Whh_f1, b_f1,
               Wih_b0, Whh_b0, b_b0, Wih_b1, Whh_b1, b_b1,
               Wlin, blin, futp, outp, h0s, h1s, h1p, threadIdx.x, blockIdx.x);
}

extern "C" void kernel_launch(void* const* d_in, const int* in_sizes, int n_in,
                              void* d_out, int out_size, void* d_ws, size_t ws_size,
                              hipStream_t stream) {
  (void)in_sizes; (void)n_in; (void)out_size; (void)d_ws; (void)ws_size;
  lstm_kernel<<<dim3(GRID), dim3(NT), 0, stream>>>(
      d_in[0], d_in[1], d_in[2], d_in[3], d_in[4], d_in[5], d_in[6],
      d_in[7], d_in[8], d_in[9], d_in[10], d_in[11], d_in[12],
      d_in[13], d_in[14], (const int*)d_in[15], d_out);
}